// Round 1
// baseline (35315.332 us; speedup 1.0000x reference)
//
#include <hip/hip_runtime.h>
#include <stdint.h>

// RK4 ODE integrator: dx/dt = W2·tanh(W1·x + b1) + b2, 64 steps, t in [0,1].
// B=4096, D=1024, H=4096. All GEMMs bf16-MFMA (16x16x32), fp32 accumulate.
// GEMM1: h = tanh(x@W1^T + b1)  [B,D]x[H,D]^T -> [B,H] (bf16 out)
// GEMM2: k = h@W2^T + b2, fused RK4 elementwise epilogue.

typedef __attribute__((ext_vector_type(8))) __bf16 bf16x8;
typedef __attribute__((ext_vector_type(4))) float floatx4;

#define TILE 128
#define BK 32

__device__ __forceinline__ unsigned short f2bf(float f) {
  union { float f; unsigned u; } v; v.f = f;
  unsigned r = v.u + 0x7fffu + ((v.u >> 16) & 1u);  // RNE
  return (unsigned short)(r >> 16);
}

__device__ __forceinline__ float tanh_fast(float x) {
  float cx = fminf(15.0f, fmaxf(-15.0f, x));
  float e = __expf(2.0f * cx);                       // v_exp_f32
  return fmaf(-2.0f, __builtin_amdgcn_rcpf(e + 1.0f), 1.0f);
}

__device__ __forceinline__ void async16(const unsigned short* g, unsigned short* l) {
  // direct global->LDS, 16B/lane; LDS dest = wave-uniform base + lane*16
  __builtin_amdgcn_global_load_lds(
      (__attribute__((address_space(1))) void*)(g),
      (__attribute__((address_space(3))) void*)(l),
      16, 0, 0);
}

// EPI: 0 = GEMM1 (bias+tanh -> bf16 hOut)
//      1 = GEMM2 rk4 first  (xacc = xf + aacc*k ; xb = bf16(xf + cnext*k))
//      2 = GEMM2 rk4 mid    (xacc += aacc*k    ; xb = bf16(xf + cnext*k))
//      3 = GEMM2 rk4 last   (xf = xacc + aacc*k; xb = bf16(xf))
template <int EPI>
__global__ __launch_bounds__(256, 2) void gemm_bt(
    const unsigned short* __restrict__ A,   // [M,K] bf16 row-major
    const unsigned short* __restrict__ Bw,  // [N,K] bf16 row-major (B^T form)
    const float* __restrict__ bias,         // [N]
    int K, int N,
    unsigned short* __restrict__ hOut,      // EPI==0: [M,N] bf16
    const float* xf_in, float* xacc, float* xf_out, unsigned short* xb,
    float aacc, float cnext) {
  __shared__ unsigned short As[TILE * BK];
  __shared__ unsigned short Bs[TILE * BK];

  const int tid  = threadIdx.x;
  const int lane = tid & 63;
  const int wv   = tid >> 6;          // 4 waves
  const int bm   = blockIdx.y * TILE;
  const int bn   = blockIdx.x * TILE;

  // --- staging coords: each wave stages 32 rows of A and of B per K-step ---
  const int sr  = lane >> 2;          // 0..15 row within 16-row group
  const int sc  = (lane & 3) << 3;    // 0,8,16,24 col (x8 bf16 = 16B)
  const int arb = wv * 32;

  const unsigned short* pA = A  + (size_t)(bm + arb + sr) * K + sc;
  const unsigned short* pB = Bw + (size_t)(bn + arb + sr) * K + sc;
  unsigned short* lA0 = &As[arb * BK];
  unsigned short* lA1 = &As[(arb + 16) * BK];
  unsigned short* lB0 = &Bs[arb * BK];
  unsigned short* lB1 = &Bs[(arb + 16) * BK];
  const size_t rstep = (size_t)16 * K;

  // --- compute coords: wave tile 64x64, 4x4 of 16x16x32 MFMAs ---
  const int wm   = (wv >> 1) * 64;
  const int wn   = (wv & 1) * 64;
  const int lrow = lane & 15;         // A m-index / B n-index / C col
  const int lk   = lane >> 4;         // k-quad; C row-group

  floatx4 acc[4][4];
#pragma unroll
  for (int i = 0; i < 4; ++i)
#pragma unroll
    for (int j = 0; j < 4; ++j) acc[i][j] = (floatx4){0.f, 0.f, 0.f, 0.f};

  for (int k0 = 0; k0 < K; k0 += BK) {
    async16(pA, lA0);
    async16(pA + rstep, lA1);
    async16(pB, lB0);
    async16(pB + rstep, lB1);
    pA += BK; pB += BK;
    asm volatile("s_waitcnt vmcnt(0)" ::: "memory");
    __syncthreads();

    bf16x8 aF[4], bF[4];
#pragma unroll
    for (int i = 0; i < 4; ++i)
      aF[i] = *(const bf16x8*)(&As[(wm + i * 16 + lrow) * BK + lk * 8]);
#pragma unroll
    for (int j = 0; j < 4; ++j)
      bF[j] = *(const bf16x8*)(&Bs[(wn + j * 16 + lrow) * BK + lk * 8]);
#pragma unroll
    for (int i = 0; i < 4; ++i)
#pragma unroll
      for (int j = 0; j < 4; ++j)
        acc[i][j] = __builtin_amdgcn_mfma_f32_16x16x32_bf16(aF[i], bF[j], acc[i][j], 0, 0, 0);
    __syncthreads();
  }

  // --- epilogue --- C/D layout: col = lane&15, row = (lane>>4)*4 + r (m89-verified)
#pragma unroll
  for (int j = 0; j < 4; ++j) {
    const int col = bn + wn + j * 16 + lrow;
    const float bcol = bias[col];
#pragma unroll
    for (int i = 0; i < 4; ++i) {
      const int row0 = bm + wm + i * 16 + lk * 4;
#pragma unroll
      for (int r = 0; r < 4; ++r) {
        const float v = acc[i][j][r] + bcol;
        const size_t idx = (size_t)(row0 + r) * N + col;
        if constexpr (EPI == 0) {
          hOut[idx] = f2bf(tanh_fast(v));
        } else if constexpr (EPI == 1) {
          const float xv = xf_in[idx];
          xacc[idx] = fmaf(aacc, v, xv);
          xb[idx] = f2bf(fmaf(cnext, v, xv));
        } else if constexpr (EPI == 2) {
          const float xv = xf_in[idx];
          xacc[idx] = fmaf(aacc, v, xacc[idx]);
          xb[idx] = f2bf(fmaf(cnext, v, xv));
        } else {
          const float xn = fmaf(aacc, v, xacc[idx]);
          xf_out[idx] = xn;
          xb[idx] = f2bf(xn);
        }
      }
    }
  }
}

__global__ void cvt_kernel(const float* __restrict__ s, unsigned short* __restrict__ d, int n4) {
  int i = blockIdx.x * 256 + threadIdx.x;
  if (i < n4) {
    float4 v = ((const float4*)s)[i];
    ((ushort4*)d)[i] = make_ushort4(f2bf(v.x), f2bf(v.y), f2bf(v.z), f2bf(v.w));
  }
}

__global__ void initx_kernel(const float* __restrict__ s, float* __restrict__ xf,
                             unsigned short* __restrict__ xb, int n4) {
  int i = blockIdx.x * 256 + threadIdx.x;
  if (i < n4) {
    float4 v = ((const float4*)s)[i];
    ((float4*)xf)[i] = v;
    ((ushort4*)xb)[i] = make_ushort4(f2bf(v.x), f2bf(v.y), f2bf(v.z), f2bf(v.w));
  }
}

extern "C" void kernel_launch(void* const* d_in, const int* in_sizes, int n_in,
                              void* d_out, int out_size, void* d_ws, size_t ws_size,
                              hipStream_t stream) {
  const float* x  = (const float*)d_in[0];
  const float* W1 = (const float*)d_in[1];
  const float* b1 = (const float*)d_in[2];
  const float* W2 = (const float*)d_in[3];
  const float* b2 = (const float*)d_in[4];
  const int H = in_sizes[2];            // 4096
  const int D = in_sizes[4];            // 1024
  const int B = in_sizes[0] / D;        // 4096

  // workspace layout (72 MB): W1b | W2b | xb | hb | xacc
  unsigned short* W1b = (unsigned short*)d_ws;
  unsigned short* W2b = W1b + (size_t)H * D;
  unsigned short* xb  = W2b + (size_t)D * H;
  unsigned short* hb  = xb + (size_t)B * D;
  float* xacc = (float*)(hb + (size_t)B * H);
  float* xf   = (float*)d_out;          // fp32 state lives in d_out

  const float dt = 1.0f / 64.0f;

  int n4 = (H * D) / 4;
  cvt_kernel<<<dim3((n4 + 255) / 256), dim3(256), 0, stream>>>(W1, W1b, n4);
  cvt_kernel<<<dim3((n4 + 255) / 256), dim3(256), 0, stream>>>(W2, W2b, n4);
  int m4 = (B * D) / 4;
  initx_kernel<<<dim3((m4 + 255) / 256), dim3(256), 0, stream>>>(x, xf, xb, m4);

  dim3 blk(256, 1, 1);
  dim3 g1(H / TILE, B / TILE, 1);       // 32 x 32
  dim3 g2(D / TILE, B / TILE, 1);       // 8 x 32

  for (int s = 0; s < 64; ++s) {
    // k1
    gemm_bt<0><<<g1, blk, 0, stream>>>(xb, W1b, b1, D, H, hb, nullptr, nullptr, nullptr, nullptr, 0.f, 0.f);
    gemm_bt<1><<<g2, blk, 0, stream>>>(hb, W2b, b2, H, D, nullptr, xf, xacc, xf, xb, dt / 6.f, dt / 2.f);
    // k2
    gemm_bt<0><<<g1, blk, 0, stream>>>(xb, W1b, b1, D, H, hb, nullptr, nullptr, nullptr, nullptr, 0.f, 0.f);
    gemm_bt<2><<<g2, blk, 0, stream>>>(hb, W2b, b2, H, D, nullptr, xf, xacc, xf, xb, dt / 3.f, dt / 2.f);
    // k3
    gemm_bt<0><<<g1, blk, 0, stream>>>(xb, W1b, b1, D, H, hb, nullptr, nullptr, nullptr, nullptr, 0.f, 0.f);
    gemm_bt<2><<<g2, blk, 0, stream>>>(hb, W2b, b2, H, D, nullptr, xf, xacc, xf, xb, dt / 3.f, dt);
    // k4
    gemm_bt<0><<<g1, blk, 0, stream>>>(xb, W1b, b1, D, H, hb, nullptr, nullptr, nullptr, nullptr, 0.f, 0.f);
    gemm_bt<3><<<g2, blk, 0, stream>>>(hb, W2b, b2, H, D, nullptr, xf, xacc, xf, xb, dt / 6.f, 0.f);
  }
}

// Round 2
// 32008.649 us; speedup vs baseline: 1.1033x; 1.1033x over previous
//
#include <hip/hip_runtime.h>
#include <stdint.h>

// RK4 ODE integrator: dx/dt = W2·tanh(W1·x + b1) + b2, 64 steps, t in [0,1].
// B=4096, D=1024, H=4096. All GEMMs bf16-MFMA (16x16x32), fp32 accumulate.
// GEMM1: h = tanh(x@W1^T + b1)  [B,D]x[H,D]^T -> [B,H] (bf16 out), TN=128
// GEMM2: k = h@W2^T + b2, fused RK4 epilogue. TN=64 (N=1024 -> 512 blocks,
//        2 blocks/CU; TN=128 gave 256 blocks = 1/CU = occupancy-starved).

typedef __attribute__((ext_vector_type(8))) __bf16 bf16x8;
typedef __attribute__((ext_vector_type(4))) float floatx4;

#define TM 128
#define BK 32

__device__ __forceinline__ unsigned short f2bf(float f) {
  union { float f; unsigned u; } v; v.f = f;
  unsigned r = v.u + 0x7fffu + ((v.u >> 16) & 1u);  // RNE
  return (unsigned short)(r >> 16);
}

__device__ __forceinline__ float tanh_fast(float x) {
  float cx = fminf(15.0f, fmaxf(-15.0f, x));
  float e = __expf(2.0f * cx);                       // v_exp_f32
  return fmaf(-2.0f, __builtin_amdgcn_rcpf(e + 1.0f), 1.0f);
}

__device__ __forceinline__ void async16(const unsigned short* g, unsigned short* l) {
  // direct global->LDS, 16B/lane; LDS dest = wave-uniform base + lane*16
  __builtin_amdgcn_global_load_lds(
      (__attribute__((address_space(1))) void*)(g),
      (__attribute__((address_space(3))) void*)(l),
      16, 0, 0);
}

// EPI: 0 = GEMM1 (bias+tanh -> bf16 hOut)
//      1 = GEMM2 rk4 first  (xacc = xf + aacc*k ; xb = bf16(xf + cnext*k))
//      2 = GEMM2 rk4 mid    (xacc += aacc*k    ; xb = bf16(xf + cnext*k))
//      3 = GEMM2 rk4 last   (xf = xacc + aacc*k; xb = bf16(xf))
// TN: 128 (wave tile 64x64, acc 4x4) or 64 (wave tile 64x32, acc 4x2)
template <int TN, int EPI>
__global__ __launch_bounds__(256, 2) void gemm_bt(
    const unsigned short* __restrict__ A,   // [M,K] bf16 row-major
    const unsigned short* __restrict__ Bw,  // [N,K] bf16 row-major (B^T form)
    const float* __restrict__ bias,         // [N]
    int K, int N,
    unsigned short* __restrict__ hOut,      // EPI==0: [M,N] bf16
    const float* xf_in, float* xacc, float* xf_out, unsigned short* xb,
    float aacc, float cnext) {
  constexpr int NJ = TN / 32;               // acc tiles in n per wave
  __shared__ unsigned short As[TM * BK];
  __shared__ unsigned short Bs[TN * BK];

  const int tid  = threadIdx.x;
  const int lane = tid & 63;
  const int wv   = tid >> 6;          // 4 waves
  const int bm   = blockIdx.y * TM;
  const int bn   = blockIdx.x * TN;

  // --- staging coords: one async16 covers 16 rows x 32 cols (1 KB) ---
  const int sr  = lane >> 2;          // 0..15 row within 16-row group
  const int sc  = (lane & 3) << 3;    // 0,8,16,24 col (x8 bf16 = 16B)
  const int arb = wv * 32;                        // A: 32 rows/wave
  const int brb = (TN == 128) ? wv * 32 : wv * 16; // B rows/wave

  const unsigned short* pA = A  + (size_t)(bm + arb + sr) * K + sc;
  const unsigned short* pB = Bw + (size_t)(bn + brb + sr) * K + sc;
  unsigned short* lA0 = &As[(arb)      * BK];
  unsigned short* lA1 = &As[(arb + 16) * BK];
  unsigned short* lB0 = &Bs[(brb)      * BK];
  unsigned short* lB1 = &Bs[(brb + 16) * BK];
  const size_t rstep = (size_t)16 * K;

  // --- compute coords ---
  const int wm   = (wv >> 1) * 64;
  const int wn   = (wv & 1) * (TN / 2);
  const int lrow = lane & 15;         // A m-index / B n-index / C col
  const int lk   = lane >> 4;         // k-quad; C row-group

  floatx4 acc[4][NJ];
#pragma unroll
  for (int i = 0; i < 4; ++i)
#pragma unroll
    for (int j = 0; j < NJ; ++j) acc[i][j] = (floatx4){0.f, 0.f, 0.f, 0.f};

  for (int k0 = 0; k0 < K; k0 += BK) {
    async16(pA, lA0);
    async16(pA + rstep, lA1);
    async16(pB, lB0);
    if (TN == 128) async16(pB + rstep, lB1);
    pA += BK; pB += BK;
    asm volatile("s_waitcnt vmcnt(0)" ::: "memory");
    __syncthreads();

    bf16x8 aF[4], bF[NJ];
#pragma unroll
    for (int i = 0; i < 4; ++i)
      aF[i] = *(const bf16x8*)(&As[(wm + i * 16 + lrow) * BK + lk * 8]);
#pragma unroll
    for (int j = 0; j < NJ; ++j)
      bF[j] = *(const bf16x8*)(&Bs[(wn + j * 16 + lrow) * BK + lk * 8]);
#pragma unroll
    for (int i = 0; i < 4; ++i)
#pragma unroll
      for (int j = 0; j < NJ; ++j)
        acc[i][j] = __builtin_amdgcn_mfma_f32_16x16x32_bf16(aF[i], bF[j], acc[i][j], 0, 0, 0);
    __syncthreads();
  }

  // --- epilogue --- C/D layout: col = lane&15, row = (lane>>4)*4 + r (m89-verified)
#pragma unroll
  for (int j = 0; j < NJ; ++j) {
    const int col = bn + wn + j * 16 + lrow;
    const float bcol = bias[col];
#pragma unroll
    for (int i = 0; i < 4; ++i) {
      const int row0 = bm + wm + i * 16 + lk * 4;
#pragma unroll
      for (int r = 0; r < 4; ++r) {
        const float v = acc[i][j][r] + bcol;
        const size_t idx = (size_t)(row0 + r) * N + col;
        if constexpr (EPI == 0) {
          hOut[idx] = f2bf(tanh_fast(v));
        } else if constexpr (EPI == 1) {
          const float xv = xf_in[idx];
          xacc[idx] = fmaf(aacc, v, xv);
          xb[idx] = f2bf(fmaf(cnext, v, xv));
        } else if constexpr (EPI == 2) {
          const float xv = xf_in[idx];
          xacc[idx] = fmaf(aacc, v, xacc[idx]);
          xb[idx] = f2bf(fmaf(cnext, v, xv));
        } else {
          const float xn = fmaf(aacc, v, xacc[idx]);
          xf_out[idx] = xn;
          xb[idx] = f2bf(xn);
        }
      }
    }
  }
}

__global__ void cvt_kernel(const float* __restrict__ s, unsigned short* __restrict__ d, int n4) {
  int i = blockIdx.x * 256 + threadIdx.x;
  if (i < n4) {
    float4 v = ((const float4*)s)[i];
    ((ushort4*)d)[i] = make_ushort4(f2bf(v.x), f2bf(v.y), f2bf(v.z), f2bf(v.w));
  }
}

__global__ void initx_kernel(const float* __restrict__ s, float* __restrict__ xf,
                             unsigned short* __restrict__ xb, int n4) {
  int i = blockIdx.x * 256 + threadIdx.x;
  if (i < n4) {
    float4 v = ((const float4*)s)[i];
    ((float4*)xf)[i] = v;
    ((ushort4*)xb)[i] = make_ushort4(f2bf(v.x), f2bf(v.y), f2bf(v.z), f2bf(v.w));
  }
}

extern "C" void kernel_launch(void* const* d_in, const int* in_sizes, int n_in,
                              void* d_out, int out_size, void* d_ws, size_t ws_size,
                              hipStream_t stream) {
  const float* x  = (const float*)d_in[0];
  const float* W1 = (const float*)d_in[1];
  const float* b1 = (const float*)d_in[2];
  const float* W2 = (const float*)d_in[3];
  const float* b2 = (const float*)d_in[4];
  const int H = in_sizes[2];            // 4096
  const int D = in_sizes[4];            // 1024
  const int B = in_sizes[0] / D;        // 4096

  // workspace layout (~72 MB): W1b | W2b | xb | hb | xacc
  unsigned short* W1b = (unsigned short*)d_ws;
  unsigned short* W2b = W1b + (size_t)H * D;
  unsigned short* xb  = W2b + (size_t)D * H;
  unsigned short* hb  = xb + (size_t)B * D;
  float* xacc = (float*)(hb + (size_t)B * H);
  float* xf   = (float*)d_out;          // fp32 state lives in d_out

  const float dt = 1.0f / 64.0f;

  int n4 = (H * D) / 4;
  cvt_kernel<<<dim3((n4 + 255) / 256), dim3(256), 0, stream>>>(W1, W1b, n4);
  cvt_kernel<<<dim3((n4 + 255) / 256), dim3(256), 0, stream>>>(W2, W2b, n4);
  int m4 = (B * D) / 4;
  initx_kernel<<<dim3((m4 + 255) / 256), dim3(256), 0, stream>>>(x, xf, xb, m4);

  dim3 blk(256, 1, 1);
  dim3 g1(H / 128, B / TM, 1);          // 32 x 32, TN=128
  dim3 g2(D / 64,  B / TM, 1);          // 16 x 32, TN=64 -> 2 blocks/CU

  for (int s = 0; s < 64; ++s) {
    // k1
    gemm_bt<128, 0><<<g1, blk, 0, stream>>>(xb, W1b, b1, D, H, hb, nullptr, nullptr, nullptr, nullptr, 0.f, 0.f);
    gemm_bt<64, 1><<<g2, blk, 0, stream>>>(hb, W2b, b2, H, D, nullptr, xf, xacc, xf, xb, dt / 6.f, dt / 2.f);
    // k2
    gemm_bt<128, 0><<<g1, blk, 0, stream>>>(xb, W1b, b1, D, H, hb, nullptr, nullptr, nullptr, nullptr, 0.f, 0.f);
    gemm_bt<64, 2><<<g2, blk, 0, stream>>>(hb, W2b, b2, H, D, nullptr, xf, xacc, xf, xb, dt / 3.f, dt / 2.f);
    // k3
    gemm_bt<128, 0><<<g1, blk, 0, stream>>>(xb, W1b, b1, D, H, hb, nullptr, nullptr, nullptr, nullptr, 0.f, 0.f);
    gemm_bt<64, 2><<<g2, blk, 0, stream>>>(hb, W2b, b2, H, D, nullptr, xf, xacc, xf, xb, dt / 3.f, dt);
    // k4
    gemm_bt<128, 0><<<g1, blk, 0, stream>>>(xb, W1b, b1, D, H, hb, nullptr, nullptr, nullptr, nullptr, 0.f, 0.f);
    gemm_bt<64, 3><<<g2, blk, 0, stream>>>(hb, W2b, b2, H, D, nullptr, xf, xacc, xf, xb, dt / 6.f, 0.f);
  }
}

// Round 3
// 30509.476 us; speedup vs baseline: 1.1575x; 1.0491x over previous
//
#include <hip/hip_runtime.h>
#include <stdint.h>

// RK4 ODE integrator: dx/dt = W2·tanh(W1·x + b1) + b2, 64 steps, t in [0,1].
// B=4096, D=1024, H=4096. All GEMMs bf16-MFMA (16x16x32), fp32 accumulate.
// GEMM1: h = tanh(x@W1^T + b1) [B,D]x[H,D]^T -> [B,H], TN=128, BK=32.
// GEMM2: k = h@W2^T + b2 fused RK4 epilogue. TN=64 (512 blocks, 2/CU),
//        BK=64 (halves barrier-drain count on the K=4096 loop; LDS 24.6 KB).

typedef __attribute__((ext_vector_type(8))) __bf16 bf16x8;
typedef __attribute__((ext_vector_type(4))) float floatx4;

#define TM 128

__device__ __forceinline__ unsigned short f2bf(float f) {
  union { float f; unsigned u; } v; v.f = f;
  unsigned r = v.u + 0x7fffu + ((v.u >> 16) & 1u);  // RNE
  return (unsigned short)(r >> 16);
}

__device__ __forceinline__ float tanh_fast(float x) {
  float cx = fminf(15.0f, fmaxf(-15.0f, x));
  float e = __expf(2.0f * cx);                       // v_exp_f32
  return fmaf(-2.0f, __builtin_amdgcn_rcpf(e + 1.0f), 1.0f);
}

__device__ __forceinline__ void async16(const unsigned short* g, unsigned short* l) {
  // direct global->LDS, 16B/lane; LDS dest = wave-uniform base + lane*16
  __builtin_amdgcn_global_load_lds(
      (__attribute__((address_space(1))) void*)(g),
      (__attribute__((address_space(3))) void*)(l),
      16, 0, 0);
}

// EPI: 0 = GEMM1 (bias+tanh -> bf16 hOut)
//      1 = GEMM2 rk4 first  (xacc = xf + aacc*k ; xb = bf16(xf + cnext*k))
//      2 = GEMM2 rk4 mid    (xacc += aacc*k    ; xb = bf16(xf + cnext*k))
//      3 = GEMM2 rk4 last   (xf = xacc + aacc*k; xb = bf16(xf))
template <int TN, int BKT, int EPI>
__global__ __launch_bounds__(256, 2) void gemm_bt(
    const unsigned short* __restrict__ A,   // [M,K] bf16 row-major
    const unsigned short* __restrict__ Bw,  // [N,K] bf16 row-major (B^T form)
    const float* __restrict__ bias,         // [N]
    int K, int N,
    unsigned short* __restrict__ hOut,      // EPI==0: [M,N] bf16
    const float* xf_in, float* xacc, float* xf_out, unsigned short* xb,
    float aacc, float cnext) {
  constexpr int NJ = TN / 32;               // acc tiles in n per wave
  constexpr int KH = BKT / 32;              // k-halves per LDS tile
  __shared__ unsigned short As[TM * BKT];
  __shared__ unsigned short Bs[TN * BKT];

  const int tid  = threadIdx.x;
  const int lane = tid & 63;
  const int wv   = tid >> 6;          // 4 waves
  const int bm   = blockIdx.y * TM;
  const int bn   = blockIdx.x * TN;

  // --- compute coords ---
  const int wm   = (wv >> 1) * 64;
  const int wn   = (wv & 1) * (TN / 2);
  const int lrow = lane & 15;         // A m-index / B n-index / C col
  const int lk   = lane >> 4;         // k-quad; C row-group

  floatx4 acc[4][NJ];
#pragma unroll
  for (int i = 0; i < 4; ++i)
#pragma unroll
    for (int j = 0; j < NJ; ++j) acc[i][j] = (floatx4){0.f, 0.f, 0.f, 0.f};

  // --- staging coords: one async16 = 64 lanes x 16B = 1 KB ---
  // BKT=32: covers 16 rows x 32 cols.  BKT=64: covers 8 rows x 64 cols.
  const int sr = (BKT == 32) ? (lane >> 2) : (lane >> 3);
  const int sc = (BKT == 32) ? ((lane & 3) << 3) : ((lane & 7) << 3);
  const int rpc = (BKT == 32) ? 16 : 8;     // rows per async16 call
  const int arb = wv * (TM / 4);            // A rows per wave
  const int brb = wv * (TN / 4);            // B rows per wave
  constexpr int NCA = (TM / 4 == 32) ? ((BKT == 32) ? 2 : 4) : ((BKT == 32) ? 1 : 2);
  constexpr int NCB = (TN / 4 == 32) ? ((BKT == 32) ? 2 : 4) : ((BKT == 32) ? 1 : 2);

  const unsigned short* pA = A  + (size_t)(bm + arb + sr) * K + sc;
  const unsigned short* pB = Bw + (size_t)(bn + brb + sr) * K + sc;

  for (int k0 = 0; k0 < K; k0 += BKT) {
#pragma unroll
    for (int c = 0; c < NCA; ++c)
      async16(pA + (size_t)(c * rpc) * K, &As[(arb + c * rpc) * BKT]);
#pragma unroll
    for (int c = 0; c < NCB; ++c)
      async16(pB + (size_t)(c * rpc) * K, &Bs[(brb + c * rpc) * BKT]);
    pA += BKT; pB += BKT;
    asm volatile("s_waitcnt vmcnt(0)" ::: "memory");
    __syncthreads();

#pragma unroll
    for (int kh = 0; kh < KH; ++kh) {
      bf16x8 aF[4], bF[NJ];
#pragma unroll
      for (int i = 0; i < 4; ++i)
        aF[i] = *(const bf16x8*)(&As[(wm + i * 16 + lrow) * BKT + kh * 32 + lk * 8]);
#pragma unroll
      for (int j = 0; j < NJ; ++j)
        bF[j] = *(const bf16x8*)(&Bs[(wn + j * 16 + lrow) * BKT + kh * 32 + lk * 8]);
#pragma unroll
      for (int i = 0; i < 4; ++i)
#pragma unroll
        for (int j = 0; j < NJ; ++j)
          acc[i][j] = __builtin_amdgcn_mfma_f32_16x16x32_bf16(aF[i], bF[j], acc[i][j], 0, 0, 0);
    }
    __syncthreads();
  }

  // --- epilogue --- C/D layout: col = lane&15, row = (lane>>4)*4 + r (m89-verified)
#pragma unroll
  for (int j = 0; j < NJ; ++j) {
    const int col = bn + wn + j * 16 + lrow;
    const float bcol = bias[col];
#pragma unroll
    for (int i = 0; i < 4; ++i) {
      const int row0 = bm + wm + i * 16 + lk * 4;
#pragma unroll
      for (int r = 0; r < 4; ++r) {
        const float v = acc[i][j][r] + bcol;
        const size_t idx = (size_t)(row0 + r) * N + col;
        if constexpr (EPI == 0) {
          hOut[idx] = f2bf(tanh_fast(v));
        } else if constexpr (EPI == 1) {
          const float xv = xf_in[idx];
          xacc[idx] = fmaf(aacc, v, xv);
          xb[idx] = f2bf(fmaf(cnext, v, xv));
        } else if constexpr (EPI == 2) {
          const float xv = xf_in[idx];
          xacc[idx] = fmaf(aacc, v, xacc[idx]);
          xb[idx] = f2bf(fmaf(cnext, v, xv));
        } else {
          const float xn = fmaf(aacc, v, xacc[idx]);
          xf_out[idx] = xn;
          xb[idx] = f2bf(xn);
        }
      }
    }
  }
}

__global__ void cvt_kernel(const float* __restrict__ s, unsigned short* __restrict__ d, int n4) {
  int i = blockIdx.x * 256 + threadIdx.x;
  if (i < n4) {
    float4 v = ((const float4*)s)[i];
    ((ushort4*)d)[i] = make_ushort4(f2bf(v.x), f2bf(v.y), f2bf(v.z), f2bf(v.w));
  }
}

__global__ void initx_kernel(const float* __restrict__ s, float* __restrict__ xf,
                             unsigned short* __restrict__ xb, int n4) {
  int i = blockIdx.x * 256 + threadIdx.x;
  if (i < n4) {
    float4 v = ((const float4*)s)[i];
    ((float4*)xf)[i] = v;
    ((ushort4*)xb)[i] = make_ushort4(f2bf(v.x), f2bf(v.y), f2bf(v.z), f2bf(v.w));
  }
}

extern "C" void kernel_launch(void* const* d_in, const int* in_sizes, int n_in,
                              void* d_out, int out_size, void* d_ws, size_t ws_size,
                              hipStream_t stream) {
  const float* x  = (const float*)d_in[0];
  const float* W1 = (const float*)d_in[1];
  const float* b1 = (const float*)d_in[2];
  const float* W2 = (const float*)d_in[3];
  const float* b2 = (const float*)d_in[4];
  const int H = in_sizes[2];            // 4096
  const int D = in_sizes[4];            // 1024
  const int B = in_sizes[0] / D;        // 4096

  // workspace layout (~72 MB): W1b | W2b | xb | hb | xacc
  unsigned short* W1b = (unsigned short*)d_ws;
  unsigned short* W2b = W1b + (size_t)H * D;
  unsigned short* xb  = W2b + (size_t)D * H;
  unsigned short* hb  = xb + (size_t)B * D;
  float* xacc = (float*)(hb + (size_t)B * H);
  float* xf   = (float*)d_out;          // fp32 state lives in d_out

  const float dt = 1.0f / 64.0f;

  int n4 = (H * D) / 4;
  cvt_kernel<<<dim3((n4 + 255) / 256), dim3(256), 0, stream>>>(W1, W1b, n4);
  cvt_kernel<<<dim3((n4 + 255) / 256), dim3(256), 0, stream>>>(W2, W2b, n4);
  int m4 = (B * D) / 4;
  initx_kernel<<<dim3((m4 + 255) / 256), dim3(256), 0, stream>>>(x, xf, xb, m4);

  dim3 blk(256, 1, 1);
  dim3 g1(H / 128, B / TM, 1);          // 32 x 32, TN=128 BK=32
  dim3 g2(D / 64,  B / TM, 1);          // 16 x 32, TN=64  BK=64

  for (int s = 0; s < 64; ++s) {
    // k1
    gemm_bt<128, 32, 0><<<g1, blk, 0, stream>>>(xb, W1b, b1, D, H, hb, nullptr, nullptr, nullptr, nullptr, 0.f, 0.f);
    gemm_bt<64, 64, 1><<<g2, blk, 0, stream>>>(hb, W2b, b2, H, D, nullptr, xf, xacc, xf, xb, dt / 6.f, dt / 2.f);
    // k2
    gemm_bt<128, 32, 0><<<g1, blk, 0, stream>>>(xb, W1b, b1, D, H, hb, nullptr, nullptr, nullptr, nullptr, 0.f, 0.f);
    gemm_bt<64, 64, 2><<<g2, blk, 0, stream>>>(hb, W2b, b2, H, D, nullptr, xf, xacc, xf, xb, dt / 3.f, dt / 2.f);
    // k3
    gemm_bt<128, 32, 0><<<g1, blk, 0, stream>>>(xb, W1b, b1, D, H, hb, nullptr, nullptr, nullptr, nullptr, 0.f, 0.f);
    gemm_bt<64, 64, 2><<<g2, blk, 0, stream>>>(hb, W2b, b2, H, D, nullptr, xf, xacc, xf, xb, dt / 3.f, dt);
    // k4
    gemm_bt<128, 32, 0><<<g1, blk, 0, stream>>>(xb, W1b, b1, D, H, hb, nullptr, nullptr, nullptr, nullptr, 0.f, 0.f);
    gemm_bt<64, 64, 3><<<g2, blk, 0, stream>>>(hb, W2b, b2, H, D, nullptr, xf, xacc, xf, xb, dt / 6.f, 0.f);
  }
}